// Round 8
// baseline (23.806 us; speedup 1.0000x reference)
//
#include <hip/hip_runtime.h>

#define Bn 4
#define Ln 512
#define Hn 768
#define Sn 100
#define Rn 100
#define En 128
#define TEn 8
#define TRn 6
#define NEGF (-1e20f)
#define H4 (Hn / 4)        // 192
#define E4 (En / 4)        // 32
#define NTHR 640           // 10 waves
#define WBLK 16            // sliding-window width
#define NJ (Ln / WBLK)     // 32
#define DCH 64             // float4 columns per win16 block
#define NDCH (H4 / DCH)    // 3

__device__ __forceinline__ float4 fmax4(float4 a, float4 b) {
    return make_float4(fmaxf(a.x, b.x), fmaxf(a.y, b.y),
                       fmaxf(a.z, b.z), fmaxf(a.w, b.w));
}

// ---------------------------------------------------------------------------
// L1: win16[b][r][:] = max over rows r..min(r+15,511) of hid[b]  (van Herk).
// Block = (b, j, dchunk): rows 16j..16j+15 windows, 64 float4 columns.
// Per thread: 16 own-block loads (indep) + <=15 next-block loads (indep),
// register-only fmax chains, 16 stores.
// ---------------------------------------------------------------------------
__global__ void __launch_bounds__(64)
win16_kernel(const float* __restrict__ hid, float* __restrict__ win) {
    int blk = blockIdx.x;                  // ((b*NJ)+j)*NDCH + c
    int c = blk % NDCH;
    int t = blk / NDCH;
    int j = t % NJ, b = t / NJ;
    int d4 = c * DCH + threadIdx.x;
    int base = j * WBLK;

    const float4* hb4 = (const float4*)(hid + (size_t)b * Ln * Hn) + d4;
    float4 row[WBLK];
    #pragma unroll
    for (int k = 0; k < WBLK; ++k)
        row[k] = hb4[(size_t)(base + k) * H4];
    // suffix max in place: row[k] = max(rows base+k .. base+15)
    #pragma unroll
    for (int k = WBLK - 2; k >= 0; --k)
        row[k] = fmax4(row[k], row[k + 1]);

    float4* w4 = (float4*)(win + ((size_t)b * Ln + base) * Hn) + d4;
    w4[0] = row[0];
    bool has_next = (j < NJ - 1);
    float4 pre = has_next ? hb4[(size_t)(base + WBLK) * H4]
                          : make_float4(NEGF, NEGF, NEGF, NEGF);
    #pragma unroll
    for (int k = 1; k < WBLK; ++k) {
        // pre = max(rows base+16 .. base+15+k)
        w4[(size_t)k * H4] = fmax4(row[k], pre);
        if (k < WBLK - 1 && has_next)
            pre = fmax4(pre, hb4[(size_t)(base + WBLK + k) * H4]);
    }
}

// wave-level contiguous-span scan -> {start, end} (valid in all lanes)
__device__ __forceinline__ void scan_span(const int* __restrict__ mask,
                                          int lane, int* start, int* end) {
    const int4* m4 = (const int4*)(mask + lane * 8);
    int4 a = m4[0], c = m4[1];
    int mm[8] = {a.x, a.y, a.z, a.w, c.x, c.y, c.z, c.w};
    int first = 0x7fffffff, last = -1;
    #pragma unroll
    for (int r = 0; r < 8; ++r) {
        if (mm[r] != 0) {
            int row = lane * 8 + r;
            first = min(first, row);
            last = max(last, row);
        }
    }
    #pragma unroll
    for (int off = 1; off < 64; off <<= 1) {
        first = min(first, __shfl_xor(first, off, 64));
        last = max(last, __shfl_xor(last, off, 64));
    }
    *start = first;
    *end = last + 1;
}

// masked max over rows [s,e): win16 stride-16 reads (cnt>=16) or raw rows.
__device__ __forceinline__ float4 wmax(const float4* __restrict__ hb4,
                                       const float4* __restrict__ wn4,
                                       int s, int e) {
    float4 m0 = make_float4(NEGF, NEGF, NEGF, NEGF);
    float4 m1 = m0;
    int cnt = e - s;
    if (cnt >= WBLK) {
        int r = s;
        for (; r + 2 * WBLK <= e; r += 2 * WBLK) {
            m0 = fmax4(m0, wn4[(size_t)r * H4]);
            m1 = fmax4(m1, wn4[(size_t)(r + WBLK) * H4]);
        }
        if (r + WBLK <= e) { m0 = fmax4(m0, wn4[(size_t)r * H4]); r += WBLK; }
        if (r < e) m1 = fmax4(m1, wn4[(size_t)(e - WBLK) * H4]);
    } else {
        int r = s;
        for (; r + 2 <= e; r += 2) {
            m0 = fmax4(m0, hb4[(size_t)r * H4]);
            m1 = fmax4(m1, hb4[(size_t)(r + 1) * H4]);
        }
        if (r < e) m0 = fmax4(m0, hb4[(size_t)r * H4]);
    }
    return fmax4(m0, m1);
}

// ---------------------------------------------------------------------------
// L2: 800 blocks x 640 threads, segment-parallel, weights prefetched.
//  entity blk: [0,192) entity | [192,384) ctx | [384,416) size
//  rel blk:    [0,192) relctx | [192,384) e0 | [384,576) e1 | [576,640) s0,s1
// ---------------------------------------------------------------------------
__global__ void __launch_bounds__(NTHR)
logits_kernel(const float* __restrict__ hid,
              const int* __restrict__ ent_mask,
              const int* __restrict__ rel_mask,
              const int* __restrict__ samp_mask,
              const int* __restrict__ relations,
              const float* __restrict__ size_emb,
              const float* __restrict__ span_w,
              const float* __restrict__ span_b,
              const float* __restrict__ rel_w,
              const float* __restrict__ rel_b,
              const float* __restrict__ win,
              float* __restrict__ out_ent,
              float* __restrict__ out_rel) {
    int blk = blockIdx.x;
    int tid = threadIdx.x;
    int lane = tid & 63, wv = tid >> 6;

    __shared__ int se[3][2];
    __shared__ float red[10][TEn];

    float acc[TEn];
    #pragma unroll
    for (int t = 0; t < TEn; ++t) acc[t] = 0.0f;

    if (blk < Bn * Sn) {
        // ================= entity logit block =================
        int b = blk / Sn;
        // weight prefetch (k4 row = tid-dependent only)
        float w32[4 * TEn];
        if (tid < 384 + E4) {
            const float4* wp = (const float4*)(span_w + (size_t)tid * 4 * TEn);
            float4* wreg = (float4*)w32;
            #pragma unroll
            for (int i = 0; i < TEn; ++i) wreg[i] = wp[i];
        }
        if (wv == 0) {
            int s0, e0;
            scan_span(ent_mask + (size_t)blk * Ln, lane, &s0, &e0);
            if (lane == 0) { se[0][0] = s0; se[0][1] = e0; }
        }
        __syncthreads();
        int start = se[0][0], end = se[0][1];
        int cnt = end - start;

        const float4* hb4 = (const float4*)(hid + (size_t)b * Ln * Hn);
        const float4* wn4 = (const float4*)(win + (size_t)b * Ln * Hn);
        float4 v = make_float4(0.f, 0.f, 0.f, 0.f);
        bool active = true;
        if (tid < 192) {
            v = wmax(hb4 + tid, wn4 + tid, start, end);
        } else if (tid < 384) {
            v = hb4[tid - 192];                               // ctx = row 0
        } else if (tid < 384 + E4) {
            v = ((const float4*)(size_emb + (size_t)cnt * En))[tid - 384];
        } else {
            active = false;
        }
        if (active) {
            const float* vp = &v.x;
            #pragma unroll
            for (int j = 0; j < 4; ++j)
                #pragma unroll
                for (int t = 0; t < TEn; ++t)
                    acc[t] += vp[j] * w32[j * TEn + t];
        }

        #pragma unroll
        for (int t = 0; t < TEn; ++t)
            #pragma unroll
            for (int off = 32; off > 0; off >>= 1)
                acc[t] += __shfl_down(acc[t], off, 64);
        if (lane == 0) {
            #pragma unroll
            for (int t = 0; t < TEn; ++t) red[wv][t] = acc[t];
        }
        __syncthreads();
        if (tid < TEn) {
            float s = span_b[tid];
            #pragma unroll
            for (int w = 0; w < 10; ++w) s += red[w][tid];
            out_ent[(size_t)blk * TEn + tid] = s;
        }
    } else {
        // ================= relation logit block =================
        int rblk = blk - Bn * Sn;              // b*R + r
        int b = rblk / Rn;
        int a0 = relations[rblk * 2 + 0];
        int a1 = relations[rblk * 2 + 1];
        bool samp = (samp_mask[rblk] == 1);

        float w24[4 * TRn];
        {
            const float4* wp = (const float4*)(rel_w + (size_t)tid * 4 * TRn);
            float4* wreg = (float4*)w24;
            #pragma unroll
            for (int i = 0; i < TRn; ++i) wreg[i] = wp[i];
        }

        if (wv == 0) {
            if (!samp) {
                int s0, e0;
                scan_span(rel_mask + (size_t)rblk * Ln, lane, &s0, &e0);
                if (lane == 0) { se[0][0] = s0; se[0][1] = e0; }
            }
        } else if (wv == 1) {
            int s1, e1;
            scan_span(ent_mask + ((size_t)b * Sn + a0) * Ln, lane, &s1, &e1);
            if (lane == 0) { se[1][0] = s1; se[1][1] = e1; }
        } else if (wv == 2) {
            int s2, e2;
            scan_span(ent_mask + ((size_t)b * Sn + a1) * Ln, lane, &s2, &e2);
            if (lane == 0) { se[2][0] = s2; se[2][1] = e2; }
        }
        __syncthreads();
        int cnt0 = se[1][1] - se[1][0];
        int cnt1 = se[2][1] - se[2][0];

        const float4* hb4 = (const float4*)(hid + (size_t)b * Ln * Hn);
        const float4* wn4 = (const float4*)(win + (size_t)b * Ln * Hn);
        float4 v = make_float4(0.f, 0.f, 0.f, 0.f);
        bool active = true;
        if (tid < 192) {
            if (samp) active = false;
            else v = wmax(hb4 + tid, wn4 + tid, se[0][0], se[0][1]);
        } else if (tid < 384) {
            int u = tid - 192;
            v = wmax(hb4 + u, wn4 + u, se[1][0], se[1][1]);
        } else if (tid < 576) {
            int u = tid - 384;
            v = wmax(hb4 + u, wn4 + u, se[2][0], se[2][1]);
        } else if (tid < 576 + E4) {
            v = ((const float4*)(size_emb + (size_t)cnt0 * En))[tid - 576];
        } else {
            v = ((const float4*)(size_emb + (size_t)cnt1 * En))[tid - 576 - E4];
        }
        if (active) {
            const float* vp = &v.x;
            #pragma unroll
            for (int j = 0; j < 4; ++j)
                #pragma unroll
                for (int t = 0; t < TRn; ++t)
                    acc[t] += vp[j] * w24[j * TRn + t];
        }

        #pragma unroll
        for (int t = 0; t < TRn; ++t)
            #pragma unroll
            for (int off = 32; off > 0; off >>= 1)
                acc[t] += __shfl_down(acc[t], off, 64);
        if (lane == 0) {
            #pragma unroll
            for (int t = 0; t < TRn; ++t) red[wv][t] = acc[t];
        }
        __syncthreads();
        if (tid < TRn) {
            float s = rel_b[tid];
            #pragma unroll
            for (int w = 0; w < 10; ++w) s += red[w][tid];
            out_rel[(size_t)rblk * TRn + tid] = s;
        }
    }
}

extern "C" void kernel_launch(void* const* d_in, const int* in_sizes, int n_in,
                              void* d_out, int out_size, void* d_ws, size_t ws_size,
                              hipStream_t stream) {
    const float* hid       = (const float*)d_in[0];   // (B,L,H)
    const int*   ent_mask  = (const int*)d_in[1];     // (B,S,L)
    const int*   relations = (const int*)d_in[2];     // (B,R,2)
    const int*   rel_mask  = (const int*)d_in[3];     // (B,R,L)
    const int*   samp_mask = (const int*)d_in[4];     // (B,R)
    const float* size_emb  = (const float*)d_in[5];   // (100,E)
    const float* span_w    = (const float*)d_in[6];   // (2H+E, TE)
    const float* span_b    = (const float*)d_in[7];   // (TE,)
    const float* rel_w     = (const float*)d_in[8];   // (3H+2E, TR)
    const float* rel_b     = (const float*)d_in[9];   // (TR,)

    float* out = (float*)d_out;
    float* out_ent = out;                       // (B,S,TE)
    float* out_rel = out + Bn * Sn * TEn;       // (B,R,TR)

    float* win = (float*)d_ws;                  // B*L*H floats (6.3 MB)

    win16_kernel<<<Bn * NJ * NDCH, 64, 0, stream>>>(hid, win);

    logits_kernel<<<Bn * (Sn + Rn), NTHR, 0, stream>>>(
        hid, ent_mask, rel_mask, samp_mask, relations, size_emb,
        span_w, span_b, rel_w, rel_b, win, out_ent, out_rel);
}